// Round 15
// baseline (258.627 us; speedup 1.0000x reference)
//
#include <hip/hip_runtime.h>
#include <hip/hip_bf16.h>
#include <math.h>

typedef unsigned short u16;
typedef unsigned int u32;
typedef __attribute__((ext_vector_type(8))) short short8;
typedef __attribute__((ext_vector_type(4))) float f32x4;

constexpr int CB = 2;
constexpr int CS = 1024;
constexpr int CD = 1024;
constexpr int CDI = 2048;
constexpr int CNC2 = 64;   // scan chunks
constexpr int CL2 = 16;    // chunk length = CS / CNC2

__device__ inline u16 f2bf(float v) {
  __hip_bfloat16 h = __float2bfloat16(v);
  return *reinterpret_cast<u16*>(&h);
}
__device__ inline float bf2f(u16 v) {
  return __uint_as_float(((u32)v) << 16);
}

__device__ inline void gload16(const void* g, void* l) {
  __builtin_amdgcn_global_load_lds((const __attribute__((address_space(1))) void*)g,
                                   (__attribute__((address_space(3))) void*)l, 16, 0, 0);
}

// ---------------- weight transposes + LN1 fused in one dispatch ----------------
// blocks [0, lnbase): fp32 in[K][N] -> bf16 out[Npad][K] (pad rows zeroed)
// blocks [lnbase, lnbase+2048): LayerNorm row -> bf16
struct TJob { const float* src; u16* dst; int K, N, gx, base; };
struct TJobs { TJob j[6]; };

__global__ __launch_bounds__(256)
void transpose_ln_kernel(TJobs jobs, int lnbase, const float* __restrict__ x,
                         const float* __restrict__ g, const float* __restrict__ bb,
                         u16* __restrict__ outb) {
  int b = blockIdx.x;
  if (b >= lnbase) {
    int row = b - lnbase;
    const float4* xr = (const float4*)(x + (size_t)row * CD);
    float4 v = xr[threadIdx.x];
    float s = v.x + v.y + v.z + v.w;
    float ss = v.x * v.x + v.y * v.y + v.z * v.z + v.w * v.w;
#pragma unroll
    for (int o = 1; o < 64; o <<= 1) { s += __shfl_xor(s, o); ss += __shfl_xor(ss, o); }
    __shared__ float sb[4], ssb[4];
    int wid = threadIdx.x >> 6;
    if ((threadIdx.x & 63) == 0) { sb[wid] = s; ssb[wid] = ss; }
    __syncthreads();
    s = sb[0] + sb[1] + sb[2] + sb[3];
    ss = ssb[0] + ssb[1] + ssb[2] + ssb[3];
    float mu = s * (1.f / CD);
    float var = ss * (1.f / CD) - mu * mu;
    float rstd = rsqrtf(var + 1e-5f);
    float4 gv = ((const float4*)g)[threadIdx.x];
    float4 bv = ((const float4*)bb)[threadIdx.x];
    ushort4 o;
    o.x = f2bf((v.x - mu) * rstd * gv.x + bv.x);
    o.y = f2bf((v.y - mu) * rstd * gv.y + bv.y);
    o.z = f2bf((v.z - mu) * rstd * gv.z + bv.z);
    o.w = f2bf((v.w - mu) * rstd * gv.w + bv.w);
    ((ushort4*)(outb + (size_t)row * CD))[threadIdx.x] = o;
    return;
  }
  int ji = 0;
#pragma unroll
  for (int i = 1; i < 6; ++i) if (b >= jobs.j[i].base) ji = i;
  TJob jb = jobs.j[ji];
  int lb = b - jb.base;
  int n0 = (lb % jb.gx) * 32, k0 = (lb / jb.gx) * 32;
  __shared__ float tile[32][33];
  int tx = threadIdx.x & 31, ty = threadIdx.x >> 5;  // 32 x 8
#pragma unroll
  for (int i = 0; i < 4; ++i) {
    int k = k0 + ty + i * 8, n = n0 + tx;
    tile[ty + i * 8][tx] = (n < jb.N) ? jb.src[(size_t)k * jb.N + n] : 0.f;
  }
  __syncthreads();
#pragma unroll
  for (int i = 0; i < 4; ++i) {
    int n = n0 + ty + i * 8, k = k0 + tx;
    jb.dst[(size_t)n * jb.K + k] = f2bf(tile[tx][ty + i * 8]);
  }
}

// ---------------- LayerNorm -> bf16 (LN2 path stays standalone via ln_fuse) ------

// ---------------- fused: x1 = x + sum(4 bf16 slabs) + b_out -> out; LN2(x1) -> outb ----------------
__global__ __launch_bounds__(256)
void ln_fuse_kernel(const float* __restrict__ x, const u16* __restrict__ S,
                    const float* __restrict__ bo, const float* __restrict__ g,
                    const float* __restrict__ bb, float* __restrict__ out,
                    u16* __restrict__ outb) {
  constexpr size_t SSTR = (size_t)2048 * 1024;  // slab stride (u16 elems)
  int row = blockIdx.x;
  float4 xv = ((const float4*)(x + (size_t)row * CD))[threadIdx.x];
  float4 bv0 = ((const float4*)bo)[threadIdx.x];
  float4 v;
  v.x = xv.x + bv0.x; v.y = xv.y + bv0.y; v.z = xv.z + bv0.z; v.w = xv.w + bv0.w;
  size_t base = (size_t)row * CD + threadIdx.x * 4;
#pragma unroll
  for (int z = 0; z < 4; ++z) {
    ushort4 sv = *(const ushort4*)(S + z * SSTR + base);
    v.x += bf2f(sv.x); v.y += bf2f(sv.y); v.z += bf2f(sv.z); v.w += bf2f(sv.w);
  }
  ((float4*)(out + (size_t)row * CD))[threadIdx.x] = v;
  float s = v.x + v.y + v.z + v.w;
  float ss = v.x * v.x + v.y * v.y + v.z * v.z + v.w * v.w;
#pragma unroll
  for (int o = 1; o < 64; o <<= 1) { s += __shfl_xor(s, o); ss += __shfl_xor(ss, o); }
  __shared__ float sb[4], ssb[4];
  int wid = threadIdx.x >> 6;
  if ((threadIdx.x & 63) == 0) { sb[wid] = s; ssb[wid] = ss; }
  __syncthreads();
  s = sb[0] + sb[1] + sb[2] + sb[3];
  ss = ssb[0] + ssb[1] + ssb[2] + ssb[3];
  float mu = s * (1.f / CD);
  float var = ss * (1.f / CD) - mu * mu;
  float rstd = rsqrtf(var + 1e-5f);
  float4 gv = ((const float4*)g)[threadIdx.x];
  float4 bv = ((const float4*)bb)[threadIdx.x];
  ushort4 o;
  o.x = f2bf((v.x - mu) * rstd * gv.x + bv.x);
  o.y = f2bf((v.y - mu) * rstd * gv.y + bv.y);
  o.z = f2bf((v.z - mu) * rstd * gv.z + bv.z);
  o.w = f2bf((v.w - mu) * rstd * gv.w + bv.w);
  ((ushort4*)(outb + (size_t)row * CD))[threadIdx.x] = o;
}

// ---------------- final: out += S0 + S1 (bf16 slabs) + b_so ----------------
__global__ __launch_bounds__(256)
void add3_kernel(float* __restrict__ out, const u16* __restrict__ S,
                 const float* __restrict__ bias) {
  constexpr size_t SSTR = (size_t)2048 * 1024;
  int idx = blockIdx.x * 256 + threadIdx.x;     // over 2M/4 groups
  int c4 = idx & 255;
  size_t base = (size_t)idx * 4;
  float4 o = ((const float4*)out)[idx];
  float4 bv = ((const float4*)bias)[c4];
  ushort4 a = *(const ushort4*)(S + base);
  ushort4 b = *(const ushort4*)(S + SSTR + base);
  o.x += bf2f(a.x) + bf2f(b.x) + bv.x;
  o.y += bf2f(a.y) + bf2f(b.y) + bv.y;
  o.z += bf2f(a.z) + bf2f(b.z) + bv.z;
  o.w += bf2f(a.w) + bf2f(b.w) + bv.w;
  ((float4*)out)[idx] = o;
}

// ---------------- bf16 MFMA GEMM: 128xBN tile, BK=32, 2-phase dbuf ----------------
// Column-major XCD chunking (R14 verified: FETCH 35->21MB). 2-way LDS aliasing benign.
// gridDim.z>1: partial_stride>0 -> bf16 store to ((u16*)C) + z*partial_stride;
//              partial_stride==0 -> atomicAdd into fp32 C.
template<int BN, int LDA, int LDB>
__global__ __launch_bounds__(256)
void gemm5_kernel(const u16* __restrict__ A, const u16* __restrict__ Bt,
                  const float* __restrict__ bias,
                  const float* __restrict__ resid, int ldr,
                  float* __restrict__ C, int ldc,
                  u16* __restrict__ aux, int auxN,
                  int partial_stride, int Nact, int K, int act) {
  constexpr int WN = BN / 32;            // n-frags per wave
  constexpr int AHALF = 128 * 32;        // 8KB per A buffer
  constexpr int BHALF = BN * 32;
  __shared__ __align__(16) u16 As[2 * AHALF];
  __shared__ __align__(16) u16 Bs[2 * BHALF];
  const int tid = threadIdx.x, lane = tid & 63, wid = tid >> 6;
  const int wr = wid >> 1, wc = wid & 1;
  // bijective XCD-chunked swizzle, column-major within chunk (B-panel L2 reuse)
  int nwg = gridDim.x * gridDim.y;
  int bid = blockIdx.y * gridDim.x + blockIdx.x;
  int swz = (bid & 7) * (nwg >> 3) + (bid >> 3);
  int bx = swz / gridDim.y, by = swz % gridDim.y;
  const int bm = by * 128, bn = bx * BN;
  const int kper = K / gridDim.z;
  const int kbeg = blockIdx.z * kper;
  const int nt = kper / 32;

  int a_src[2], b_src[BN / 64];
#pragma unroll
  for (int j = 0; j < 2; ++j) {
    int c = tid + j * 256;
    int row = c >> 2, kc = (c & 3) ^ ((row + (row >> 2)) & 3);
    a_src[j] = (bm + row) * LDA + kc * 8 + kbeg;
  }
#pragma unroll
  for (int j = 0; j < BN / 64; ++j) {
    int c = tid + j * 256;
    int row = c >> 2, kc = (c & 3) ^ ((row + (row >> 2)) & 3);
    b_src[j] = (bn + row) * LDB + kc * 8 + kbeg;
  }
  int afo[4], bfo[WN];
  const int ch = lane >> 4;
#pragma unroll
  for (int m = 0; m < 4; ++m) {
    int r = wr * 64 + m * 16 + (lane & 15);
    afo[m] = r * 32 + ((ch ^ ((r + (r >> 2)) & 3)) << 3);
  }
#pragma unroll
  for (int n = 0; n < WN; ++n) {
    int r = wc * (BN / 2) + n * 16 + (lane & 15);
    bfo[n] = r * 32 + ((ch ^ ((r + (r >> 2)) & 3)) << 3);
  }
  f32x4 acc[4][WN] = {};

  auto stage = [&](int t, int abuf, int bbuf) {
    int k0 = t * 32;
#pragma unroll
    for (int j = 0; j < 2; ++j)
      gload16(A + a_src[j] + k0, As + abuf + (tid + j * 256) * 8);
#pragma unroll
    for (int j = 0; j < BN / 64; ++j)
      gload16(Bt + b_src[j] + k0, Bs + bbuf + (tid + j * 256) * 8);
  };
  auto compute = [&](int abuf, int bbuf) {
    short8 af[4], bfr[WN];
#pragma unroll
    for (int m = 0; m < 4; ++m) af[m] = *(const short8*)&As[abuf + afo[m]];
#pragma unroll
    for (int n = 0; n < WN; ++n) bfr[n] = *(const short8*)&Bs[bbuf + bfo[n]];
#pragma unroll
    for (int m = 0; m < 4; ++m)
#pragma unroll
      for (int n = 0; n < WN; ++n)
        acc[m][n] = __builtin_amdgcn_mfma_f32_16x16x32_bf16(af[m], bfr[n], acc[m][n], 0, 0, 0);
  };

  stage(0, 0, 0);
  __syncthreads();
  int t = 0;
  while (true) {
    if (t + 1 < nt) stage(t + 1, AHALF, BHALF);
    compute(0, 0);
    __syncthreads();
    if (++t == nt) break;
    if (t + 1 < nt) stage(t + 1, 0, 0);
    compute(AHALF, BHALF);
    __syncthreads();
    if (++t == nt) break;
  }

  const int fr = lane & 15, fq = lane >> 4;
  const int ksegs = gridDim.z;
  u16* Cp = (u16*)C + (size_t)blockIdx.z * partial_stride;
#pragma unroll
  for (int m = 0; m < 4; ++m) {
#pragma unroll
    for (int n = 0; n < WN; ++n) {
#pragma unroll
      for (int j = 0; j < 4; ++j) {
        int row = bm + wr * 64 + m * 16 + fq * 4 + j;
        int col = bn + wc * (BN / 2) + n * 16 + fr;
        if (col < Nact) {
          float v = acc[m][n][j];
          if (ksegs == 1) {
            if (bias) v += bias[col];
            if (resid) v += resid[(size_t)row * ldr + col];
            if (act == 1) v = (v > 20.f) ? v : log1pf(__expf(v));  // softplus
            if (C) C[(size_t)row * ldc + col] = v;
            if (aux && col < auxN) aux[(size_t)row * auxN + col] = f2bf(v);
          } else if (partial_stride > 0) {
            Cp[(size_t)row * ldc + col] = f2bf(v);   // bf16 partial slab
          } else {
            atomicAdd(&C[(size_t)row * ldc + col], v);
          }
        }
      }
    }
  }
}

// ---------------- conv (K=4) + silu -> bf16, x8; sums 2 xz slabs + folds b_in ----------------
// xp[t][d] = slab0 + slab1 + b_in[d]; zero-padded taps (tt<0) contribute 0 (no bias).
__global__ __launch_bounds__(256)
void conv_silu_kernel(const u16* __restrict__ xz, const float* __restrict__ bin,
                      const float* __restrict__ w, const float* __restrict__ cb,
                      u16* __restrict__ xcb) {
  constexpr size_t XSTR = (size_t)2048 * 4096;  // xz slab stride (u16)
  int idx = blockIdx.x * 256 + threadIdx.x;  // CB*CS*CDI/8 = 524288
  int d0 = (idx & 255) * 8;
  int t = (idx >> 8) & (CS - 1);
  int b = idx >> 18;
  const u16* base = xz + (size_t)(b * CS) * 4096 + d0;
  float acc[8], bi[8];
  float4 cb2[2] = { ((const float4*)(cb + d0))[0], ((const float4*)(cb + d0))[1] };
  float4 bi2[2] = { ((const float4*)(bin + d0))[0], ((const float4*)(bin + d0))[1] };
#pragma unroll
  for (int i = 0; i < 8; ++i) { acc[i] = ((const float*)cb2)[i]; bi[i] = ((const float*)bi2)[i]; }
#pragma unroll
  for (int k = 0; k < 4; ++k) {
    int tt = t - 3 + k;
    if (tt >= 0) {
      short8 v0 = *(const short8*)(base + (size_t)tt * 4096);
      short8 v1 = *(const short8*)(base + XSTR + (size_t)tt * 4096);
#pragma unroll
      for (int i = 0; i < 8; ++i) {
        float xpv = bf2f((u16)v0[i]) + bf2f((u16)v1[i]) + bi[i];
        acc[i] = fmaf(xpv, w[(d0 + i) * 4 + k], acc[i]);
      }
    }
  }
  short8 o;
#pragma unroll
  for (int i = 0; i < 8; ++i) {
    float v = acc[i] * (1.f / (1.f + __expf(-acc[i])));
    o[i] = (short)f2bf(v);
  }
  *(short8*)(xcb + (size_t)(b * CS + t) * CDI + d0) = o;
}

// ---------------- dbc combine: sum 16 bf16 partial slabs -> dbc fp32 + dtr_bf ----------------
__global__ __launch_bounds__(256)
void dbc_combine_kernel(const u16* __restrict__ parts, float* __restrict__ dbc,
                        u16* __restrict__ dtrb) {
  int idx = blockIdx.x * 256 + threadIdx.x;  // 2048 * 24
  int row = idx / 24, c4 = idx % 24;
  int o = row * 96 + c4 * 4;
  float4 s = make_float4(0.f, 0.f, 0.f, 0.f);
#pragma unroll
  for (int z = 0; z < 16; ++z) {
    ushort4 v = *(const ushort4*)(parts + (size_t)z * (2048 * 96) + o);
    s.x += bf2f(v.x); s.y += bf2f(v.y); s.z += bf2f(v.z); s.w += bf2f(v.w);
  }
  *(float4*)(dbc + o) = s;
  if (c4 < 16) {
    ushort4 b;
    b.x = f2bf(s.x); b.y = f2bf(s.y); b.z = f2bf(s.z); b.w = f2bf(s.w);
    *(ushort4*)(dtrb + row * 64 + c4 * 4) = b;
  }
}

// ---------------- selective scan: thread per (b,chunk,d), N=16 in registers ----------------
__global__ __launch_bounds__(256)
void scan1_kernel(const u16* __restrict__ dtb, const u16* __restrict__ xcb,
                  const float* __restrict__ dbc, const float* __restrict__ A_log,
                  u16* __restrict__ P, u16* __restrict__ Q) {
  int gid = blockIdx.x * 256 + threadIdx.x;  // CB*CNC2*CDI = 262144
  int d = gid & (CDI - 1);
  int c = (gid >> 11) & (CNC2 - 1);
  int b = gid >> 17;
  float acoef[16];
#pragma unroll
  for (int j = 0; j < 4; ++j) {
    float4 al = ((const float4*)(A_log + d * 16))[j];
    acoef[j * 4 + 0] = -__expf(al.x);
    acoef[j * 4 + 1] = -__expf(al.y);
    acoef[j * 4 + 2] = -__expf(al.z);
    acoef[j * 4 + 3] = -__expf(al.w);
  }
  float Pv[16], Qv[16];
#pragma unroll
  for (int n = 0; n < 16; ++n) { Pv[n] = 1.f; Qv[n] = 0.f; }
  size_t rowbase = (size_t)b * CS + (size_t)c * CL2;
  for (int i = 0; i < CL2; ++i) {
    size_t r = rowbase + i;
    float dtv = bf2f(dtb[r * CDI + d]);
    float xcv = bf2f(xcb[r * CDI + d]);
    float dx = dtv * xcv;
    const float4* bs4 = (const float4*)(dbc + r * 96 + 64);
    float bs[16];
#pragma unroll
    for (int j = 0; j < 4; ++j) {
      float4 t4 = bs4[j];
      bs[j * 4 + 0] = t4.x; bs[j * 4 + 1] = t4.y; bs[j * 4 + 2] = t4.z; bs[j * 4 + 3] = t4.w;
    }
#pragma unroll
    for (int n = 0; n < 16; ++n) {
      float a = __expf(dtv * acoef[n]);
      Pv[n] *= a;
      Qv[n] = fmaf(a, Qv[n], dx * bs[n]);
    }
  }
  size_t o = (((size_t)b * CNC2 + c) * CDI + d) * 16;
  u16 pb[16], qb[16];
#pragma unroll
  for (int n = 0; n < 16; ++n) { pb[n] = f2bf(Pv[n]); qb[n] = f2bf(Qv[n]); }
#pragma unroll
  for (int j = 0; j < 2; ++j) {
    *(short8*)(P + o + j * 8) = *(short8*)(pb + j * 8);
    *(short8*)(Q + o + j * 8) = *(short8*)(qb + j * 8);
  }
}

__global__ __launch_bounds__(256)
void scan2_kernel(const u16* __restrict__ P, u16* __restrict__ Q) {
  int gid = blockIdx.x * 256 + threadIdx.x;  // CB*CDI*16 = 65536
  int n = gid & 15;
  int d = (gid >> 4) & (CDI - 1);
  int b = gid >> 15;
  int obase = ((b * CNC2) * CDI + d) * 16 + n;
  constexpr int CSTRIDE = CDI * 16;
  float h = 0.f;
  for (int c0 = 0; c0 < CNC2; c0 += 8) {
    float pv[8], qv[8];
#pragma unroll
    for (int i = 0; i < 8; ++i) {
      int o = obase + (c0 + i) * CSTRIDE;
      pv[i] = bf2f(P[o]);
      qv[i] = bf2f(Q[o]);
    }
#pragma unroll
    for (int i = 0; i < 8; ++i) {
      int o = obase + (c0 + i) * CSTRIDE;
      Q[o] = f2bf(h);
      h = fmaf(pv[i], h, qv[i]);
    }
  }
}

__global__ __launch_bounds__(256)
void scan3_kernel(const u16* __restrict__ dtb, const u16* __restrict__ xcb,
                  const float* __restrict__ dbc, const float* __restrict__ A_log,
                  const u16* __restrict__ Q, const u16* __restrict__ xz,
                  const float* __restrict__ bin, const float* __restrict__ Dskip,
                  u16* __restrict__ y2b) {
  constexpr size_t XSTR = (size_t)2048 * 4096;
  int gid = blockIdx.x * 256 + threadIdx.x;  // 262144
  int d = gid & (CDI - 1);
  int c = (gid >> 11) & (CNC2 - 1);
  int b = gid >> 17;
  float acoef[16];
#pragma unroll
  for (int j = 0; j < 4; ++j) {
    float4 al = ((const float4*)(A_log + d * 16))[j];
    acoef[j * 4 + 0] = -__expf(al.x);
    acoef[j * 4 + 1] = -__expf(al.y);
    acoef[j * 4 + 2] = -__expf(al.z);
    acoef[j * 4 + 3] = -__expf(al.w);
  }
  float h[16];
  size_t o = (((size_t)b * CNC2 + c) * CDI + d) * 16;
#pragma unroll
  for (int j = 0; j < 2; ++j) {
    short8 q8 = *(const short8*)(Q + o + j * 8);
#pragma unroll
    for (int n = 0; n < 8; ++n) h[j * 8 + n] = bf2f((u16)q8[n]);
  }
  float dsk = Dskip[d];
  float bz = bin[2048 + d];
  size_t rowbase = (size_t)b * CS + (size_t)c * CL2;
  for (int i = 0; i < CL2; ++i) {
    size_t r = rowbase + i;
    float dtv = bf2f(dtb[r * CDI + d]);
    float xcv = bf2f(xcb[r * CDI + d]);
    size_t zo = r * 4096 + 2048 + d;
    float zv = bf2f(xz[zo]) + bf2f(xz[XSTR + zo]) + bz;
    float dx = dtv * xcv;
    const float4* bc4 = (const float4*)(dbc + r * 96 + 64);
    float bs[16], cs[16];
#pragma unroll
    for (int j = 0; j < 4; ++j) {
      float4 t4 = bc4[j];
      bs[j * 4 + 0] = t4.x; bs[j * 4 + 1] = t4.y; bs[j * 4 + 2] = t4.z; bs[j * 4 + 3] = t4.w;
      float4 u4 = bc4[4 + j];
      cs[j * 4 + 0] = u4.x; cs[j * 4 + 1] = u4.y; cs[j * 4 + 2] = u4.z; cs[j * 4 + 3] = u4.w;
    }
    float y = 0.f;
#pragma unroll
    for (int n = 0; n < 16; ++n) {
      float a = __expf(dtv * acoef[n]);
      h[n] = fmaf(a, h[n], dx * bs[n]);
      y = fmaf(h[n], cs[n], y);
    }
    float sz = zv * (1.f / (1.f + __expf(-zv)));
    y2b[r * CDI + d] = f2bf((y + xcv * dsk) * sz);
  }
}

// ---------------- soliton stencil -> bf16 (u = S2a + S2b bf16 slabs; b_si added to u0
// only — a per-d constant bias cancels exactly in the ux/uxx/uxxx stencils) ----------------
__global__ __launch_bounds__(256)
void soliton_kernel(const u16* __restrict__ S, const float* __restrict__ bsi,
                    const float* __restrict__ gates, const float* __restrict__ alpha,
                    u16* __restrict__ sol) {
  constexpr size_t SSTR = (size_t)2048 * 1024;
  int idx = blockIdx.x * 256 + threadIdx.x;  // CB*CS*CD = 2M
  int d = idx & (CD - 1);
  int t = (idx >> 10) & (CS - 1);
  int b = idx >> 20;
  int h = d >> 6;
  size_t base = (size_t)b * CS * CD + d;
  int tm2 = max(t - 2, 0), tm1 = max(t - 1, 0);
  int tp1 = min(t + 1, CS - 1), tp2 = min(t + 2, CS - 1);
  auto val = [&](int tt) {
    size_t off = base + (size_t)tt * CD;
    return bf2f(S[off]) + bf2f(S[SSTR + off]);
  };
  float um2 = val(tm2);
  float um1 = val(tm1);
  float u0r = val(t);
  float up1 = val(tp1);
  float up2 = val(tp2);
  float u0 = u0r + bsi[d];
  float ux   = (up1 - um1) * 0.5f;
  float uxx  = up1 - 2.f * u0r + um1;
  float uxxx = (up2 - 2.f * up1 + 2.f * um1 - um2) * 0.5f;
  float sg = sinf(u0);
  float kdv = -6.f * u0 * ux - uxxx;
  float hj = (1.f + alpha[h] * u0) * uxx;
  float du = gates[h * 3 + 0] * sg + gates[h * 3 + 1] * kdv + gates[h * 3 + 2] * hj;
  sol[idx] = f2bf(0.1f * du);
}

extern "C" void kernel_launch(void* const* d_in, const int* in_sizes, int n_in,
                              void* d_out, int out_size, void* d_ws, size_t ws_size,
                              hipStream_t stream) {
  const float* x      = (const float*)d_in[0];
  const float* ln1_g  = (const float*)d_in[1];
  const float* ln1_b  = (const float*)d_in[2];
  const float* W_in   = (const float*)d_in[3];
  const float* b_in   = (const float*)d_in[4];
  const float* conv_w = (const float*)d_in[5];
  const float* conv_b = (const float*)d_in[6];
  const float* W_xp   = (const float*)d_in[7];
  const float* W_dt   = (const float*)d_in[8];
  const float* b_dt   = (const float*)d_in[9];
  const float* A_log  = (const float*)d_in[10];
  const float* D_skip = (const float*)d_in[11];
  const float* W_out  = (const float*)d_in[12];
  const float* b_out  = (const float*)d_in[13];
  const float* ln2_g  = (const float*)d_in[14];
  const float* ln2_b  = (const float*)d_in[15];
  const float* W_si   = (const float*)d_in[16];
  const float* b_si   = (const float*)d_in[17];
  const float* gates  = (const float*)d_in[18];
  const float* alpha  = (const float*)d_in[19];
  const float* W_so   = (const float*)d_in[20];
  const float* b_so   = (const float*)d_in[21];
  float* out = (float*)d_out;

  float* ws = (float*)d_ws;
  size_t off = 0;
  auto alloc = [&](size_t nwords) { float* p = ws + off; off += nwords; return p; };
  const size_t BS = (size_t)CB * CS;  // 2048 rows
  const size_t M1 = 1024 * 1024;

  u16* Wt_in  = (u16*)alloc(2 * M1);       // 4096x1024 bf16
  u16* Wt_xp  = (u16*)alloc(128 * 1024);   // 128x2048 bf16 (padded 96->128)
  u16* Wt_dt  = (u16*)alloc(64 * 1024);    // 2048x64 bf16
  u16* Wt_out = (u16*)alloc(M1);           // 1024x2048 bf16
  u16* Wt_si  = (u16*)alloc(M1 / 2);       // 1024x1024 bf16
  u16* Wt_so  = (u16*)alloc(M1 / 2);
  u16* u_bf   = (u16*)alloc(M1);           // 2048x1024 bf16; alias sol_bf
  u16* sol_bf = u_bf;
  u16* xz_bf  = (u16*)alloc(8 * M1);       // 2 slabs x 2048x4096 bf16 (32MB)
  u16* dt_bf  = (u16*)alloc(2 * M1);       // 2048x2048 bf16
  u16* xc_bf  = (u16*)alloc(2 * M1);       // 2048x2048 bf16
  float* dbc  = alloc(BS * 96);
  u16* dtr_bf = (u16*)alloc(64 * 1024);    // 2048x64 bf16
  float* Pb_f = alloc(2 * M1);             // 8MB: partial slabs / scan P
  float* Qb_f = alloc(2 * M1);             // 8MB: partial slabs spill / scan Q
  u16* Pb = (u16*)Pb_f;
  u16* Qb = (u16*)Qb_f;
  u16* Slab = (u16*)Pb_f;                  // bf16 partial-slab base (up to 4 x 2M u16)
  u16* y2_bf  = (u16*)alloc(2 * M1);       // 2048x2048 bf16

  dim3 blk(256);
  const int PSTRIDE  = (int)(BS * CD);     // 2M u16 per split-K partial slab
  const int XZSTRIDE = (int)(BS * 4096);   // 8M u16 per xz slab
  const int DBC_STRIDE = 2048 * 96;        // u16 per dbc partial slab

  // 0. weight transposes + LN1 fused in one dispatch
  {
    TJobs jobs;
    int base = 0;
    auto mk = [&](const float* s, u16* dst, int K, int N, int Npad) {
      int gx = Npad / 32, gy = K / 32;
      TJob j{s, dst, K, N, gx, base};
      base += gx * gy;
      return j;
    };
    jobs.j[0] = mk(W_in, Wt_in, 1024, 4096, 4096);
    jobs.j[1] = mk(W_xp, Wt_xp, 2048, 96, 128);
    jobs.j[2] = mk(W_dt, Wt_dt, 64, 2048, 2048);
    jobs.j[3] = mk(W_out, Wt_out, 2048, 1024, 1024);
    jobs.j[4] = mk(W_si, Wt_si, 1024, 1024, 1024);
    jobs.j[5] = mk(W_so, Wt_so, 1024, 1024, 1024);
    transpose_ln_kernel<<<base + (int)BS, blk, 0, stream>>>(jobs, base, x, ln1_g, ln1_b, u_bf);
  }

  // 1. xz = u @ W_in (split-K=2 bf16 slabs; b_in folded into conv/scan3)
  gemm5_kernel<64, 1024, 1024><<<dim3(64, 16, 2), blk, 0, stream>>>(
      u_bf, Wt_in, nullptr, nullptr, 0, (float*)xz_bf, 4096, nullptr, 0, XZSTRIDE, 4096, 1024, 0);
  // 2. xc = silu(conv(slab0+slab1+b_in) + conv_b) -> bf16
  conv_silu_kernel<<<(BS * CDI) / (256 * 8), blk, 0, stream>>>(xz_bf, b_in, conv_w, conv_b, xc_bf);
  // 3. dbc partials: split-K=16, bf16 slabs into Slab (512 blocks)
  gemm5_kernel<64, 2048, 2048><<<dim3(2, 16, 16), blk, 0, stream>>>(
      xc_bf, Wt_xp, nullptr, nullptr, 0, (float*)Slab, 96, nullptr, 0, DBC_STRIDE, 96, 2048, 0);
  // 4. combine slabs -> dbc fp32 + dtr_bf
  dbc_combine_kernel<<<(2048 * 24) / 256, blk, 0, stream>>>(Slab, dbc, dtr_bf);
  // 5. dt = softplus(dtr @ W_dt + b_dt) -> bf16 (512 blocks)
  gemm5_kernel<64, 64, 64><<<dim3(32, 16), blk, 0, stream>>>(
      dtr_bf, Wt_dt, b_dt, nullptr, 0, nullptr, 0, dt_bf, 2048, 0, 2048, 64, 1);
  // 6-8. chunked selective scan (N in registers; overwrites Pb/Qb)
  scan1_kernel<<<(CB * CNC2 * CDI) / 256, blk, 0, stream>>>(dt_bf, xc_bf, dbc, A_log, Pb, Qb);
  scan2_kernel<<<(CB * CDI * 16) / 256, blk, 0, stream>>>(Pb, Qb);
  scan3_kernel<<<(CB * CNC2 * CDI) / 256, blk, 0, stream>>>(dt_bf, xc_bf, dbc, A_log, Qb, xz_bf, b_in, D_skip, y2_bf);
  // 9. W_out split-K=4 bf16 partials -> Slab[0..3] (1024 blocks)
  gemm5_kernel<64, 2048, 2048><<<dim3(16, 16, 4), blk, 0, stream>>>(
      y2_bf, Wt_out, nullptr, nullptr, 0, (float*)Slab, CD, nullptr, 0, PSTRIDE, 1024, 2048, 0);
  // 10. x1 = x + sum(4 slabs) + b_out -> out; LN2(x1) -> u_bf
  ln_fuse_kernel<<<BS, blk, 0, stream>>>(x, Slab, b_out, ln2_g, ln2_b, out, u_bf);
  // 11. W_si split-K=2 bf16 partials -> Slab[0..1] (b_si added inside soliton)
  gemm5_kernel<64, 1024, 1024><<<dim3(16, 16, 2), blk, 0, stream>>>(
      u_bf, Wt_si, nullptr, nullptr, 0, (float*)Slab, CD, nullptr, 0, PSTRIDE, 1024, 1024, 0);
  // 12. sol = 0.1 * du(slab0 + slab1 + b_si) -> bf16
  soliton_kernel<<<(BS * CD) / 256, blk, 0, stream>>>(Slab, b_si, gates, alpha, sol_bf);
  // 13. W_so split-K=2 bf16 partials -> Slab[0..1]
  gemm5_kernel<64, 1024, 1024><<<dim3(16, 16, 2), blk, 0, stream>>>(
      sol_bf, Wt_so, nullptr, nullptr, 0, (float*)Slab, CD, nullptr, 0, PSTRIDE, 1024, 1024, 0);
  // 14. out = x1 + slab0 + slab1 + b_so
  add3_kernel<<<(BS * CD) / (256 * 4), blk, 0, stream>>>(out, Slab, b_so);
}

// Round 16
// 244.079 us; speedup vs baseline: 1.0596x; 1.0596x over previous
//
#include <hip/hip_runtime.h>
#include <hip/hip_bf16.h>
#include <math.h>

typedef unsigned short u16;
typedef unsigned int u32;
typedef __attribute__((ext_vector_type(8))) short short8;
typedef __attribute__((ext_vector_type(4))) float f32x4;

constexpr int CB = 2;
constexpr int CS = 1024;
constexpr int CD = 1024;
constexpr int CDI = 2048;
constexpr int CNC2 = 64;   // scan chunks
constexpr int CL2 = 16;    // chunk length = CS / CNC2

__device__ inline u16 f2bf(float v) {
  __hip_bfloat16 h = __float2bfloat16(v);
  return *reinterpret_cast<u16*>(&h);
}
__device__ inline float bf2f(u16 v) {
  return __uint_as_float(((u32)v) << 16);
}

__device__ inline void gload16(const void* g, void* l) {
  __builtin_amdgcn_global_load_lds((const __attribute__((address_space(1))) void*)g,
                                   (__attribute__((address_space(3))) void*)l, 16, 0, 0);
}

// ---------------- weight transposes + LN1 fused in one dispatch ----------------
// blocks [0, lnbase): fp32 in[K][N] -> bf16 out[Npad][K] (pad rows zeroed)
// blocks [lnbase, lnbase+2048): LayerNorm row -> bf16
struct TJob { const float* src; u16* dst; int K, N, gx, base; };
struct TJobs { TJob j[6]; };

__global__ __launch_bounds__(256)
void transpose_ln_kernel(TJobs jobs, int lnbase, const float* __restrict__ x,
                         const float* __restrict__ g, const float* __restrict__ bb,
                         u16* __restrict__ outb) {
  int b = blockIdx.x;
  if (b >= lnbase) {
    int row = b - lnbase;
    const float4* xr = (const float4*)(x + (size_t)row * CD);
    float4 v = xr[threadIdx.x];
    float s = v.x + v.y + v.z + v.w;
    float ss = v.x * v.x + v.y * v.y + v.z * v.z + v.w * v.w;
#pragma unroll
    for (int o = 1; o < 64; o <<= 1) { s += __shfl_xor(s, o); ss += __shfl_xor(ss, o); }
    __shared__ float sb[4], ssb[4];
    int wid = threadIdx.x >> 6;
    if ((threadIdx.x & 63) == 0) { sb[wid] = s; ssb[wid] = ss; }
    __syncthreads();
    s = sb[0] + sb[1] + sb[2] + sb[3];
    ss = ssb[0] + ssb[1] + ssb[2] + ssb[3];
    float mu = s * (1.f / CD);
    float var = ss * (1.f / CD) - mu * mu;
    float rstd = rsqrtf(var + 1e-5f);
    float4 gv = ((const float4*)g)[threadIdx.x];
    float4 bv = ((const float4*)bb)[threadIdx.x];
    ushort4 o;
    o.x = f2bf((v.x - mu) * rstd * gv.x + bv.x);
    o.y = f2bf((v.y - mu) * rstd * gv.y + bv.y);
    o.z = f2bf((v.z - mu) * rstd * gv.z + bv.z);
    o.w = f2bf((v.w - mu) * rstd * gv.w + bv.w);
    ((ushort4*)(outb + (size_t)row * CD))[threadIdx.x] = o;
    return;
  }
  int ji = 0;
#pragma unroll
  for (int i = 1; i < 6; ++i) if (b >= jobs.j[i].base) ji = i;
  TJob jb = jobs.j[ji];
  int lb = b - jb.base;
  int n0 = (lb % jb.gx) * 32, k0 = (lb / jb.gx) * 32;
  __shared__ float tile[32][33];
  int tx = threadIdx.x & 31, ty = threadIdx.x >> 5;  // 32 x 8
#pragma unroll
  for (int i = 0; i < 4; ++i) {
    int k = k0 + ty + i * 8, n = n0 + tx;
    tile[ty + i * 8][tx] = (n < jb.N) ? jb.src[(size_t)k * jb.N + n] : 0.f;
  }
  __syncthreads();
#pragma unroll
  for (int i = 0; i < 4; ++i) {
    int n = n0 + ty + i * 8, k = k0 + tx;
    jb.dst[(size_t)n * jb.K + k] = f2bf(tile[tx][ty + i * 8]);
  }
}

// ---------------- fused: x1 = x + sum(4 bf16 slabs) + b_out -> out; LN2(x1) -> outb ----------------
__global__ __launch_bounds__(256)
void ln_fuse_kernel(const float* __restrict__ x, const u16* __restrict__ S,
                    const float* __restrict__ bo, const float* __restrict__ g,
                    const float* __restrict__ bb, float* __restrict__ out,
                    u16* __restrict__ outb) {
  constexpr size_t SSTR = (size_t)2048 * 1024;  // slab stride (u16 elems)
  int row = blockIdx.x;
  float4 xv = ((const float4*)(x + (size_t)row * CD))[threadIdx.x];
  float4 bv0 = ((const float4*)bo)[threadIdx.x];
  float4 v;
  v.x = xv.x + bv0.x; v.y = xv.y + bv0.y; v.z = xv.z + bv0.z; v.w = xv.w + bv0.w;
  size_t base = (size_t)row * CD + threadIdx.x * 4;
#pragma unroll
  for (int z = 0; z < 4; ++z) {
    ushort4 sv = *(const ushort4*)(S + z * SSTR + base);
    v.x += bf2f(sv.x); v.y += bf2f(sv.y); v.z += bf2f(sv.z); v.w += bf2f(sv.w);
  }
  ((float4*)(out + (size_t)row * CD))[threadIdx.x] = v;
  float s = v.x + v.y + v.z + v.w;
  float ss = v.x * v.x + v.y * v.y + v.z * v.z + v.w * v.w;
#pragma unroll
  for (int o = 1; o < 64; o <<= 1) { s += __shfl_xor(s, o); ss += __shfl_xor(ss, o); }
  __shared__ float sb[4], ssb[4];
  int wid = threadIdx.x >> 6;
  if ((threadIdx.x & 63) == 0) { sb[wid] = s; ssb[wid] = ss; }
  __syncthreads();
  s = sb[0] + sb[1] + sb[2] + sb[3];
  ss = ssb[0] + ssb[1] + ssb[2] + ssb[3];
  float mu = s * (1.f / CD);
  float var = ss * (1.f / CD) - mu * mu;
  float rstd = rsqrtf(var + 1e-5f);
  float4 gv = ((const float4*)g)[threadIdx.x];
  float4 bv = ((const float4*)bb)[threadIdx.x];
  ushort4 o;
  o.x = f2bf((v.x - mu) * rstd * gv.x + bv.x);
  o.y = f2bf((v.y - mu) * rstd * gv.y + bv.y);
  o.z = f2bf((v.z - mu) * rstd * gv.z + bv.z);
  o.w = f2bf((v.w - mu) * rstd * gv.w + bv.w);
  ((ushort4*)(outb + (size_t)row * CD))[threadIdx.x] = o;
}

// ---------------- final: out += S0 + S1 (bf16 slabs) + b_so ----------------
__global__ __launch_bounds__(256)
void add3_kernel(float* __restrict__ out, const u16* __restrict__ S,
                 const float* __restrict__ bias) {
  constexpr size_t SSTR = (size_t)2048 * 1024;
  int idx = blockIdx.x * 256 + threadIdx.x;     // over 2M/4 groups
  int c4 = idx & 255;
  size_t base = (size_t)idx * 4;
  float4 o = ((const float4*)out)[idx];
  float4 bv = ((const float4*)bias)[c4];
  ushort4 a = *(const ushort4*)(S + base);
  ushort4 b = *(const ushort4*)(S + SSTR + base);
  o.x += bf2f(a.x) + bf2f(b.x) + bv.x;
  o.y += bf2f(a.y) + bf2f(b.y) + bv.y;
  o.z += bf2f(a.z) + bf2f(b.z) + bv.z;
  o.w += bf2f(a.w) + bf2f(b.w) + bv.w;
  ((float4*)out)[idx] = o;
}

// ---------------- bf16 MFMA GEMM: 128xBN tile, BK=32, 2-phase dbuf (R14 best) ----------------
// Column-major XCD chunking (R14 verified: FETCH 35->21MB). 2-way LDS aliasing benign.
// gridDim.z>1: partial_stride>0 -> bf16 store to ((u16*)C) + z*partial_stride;
//              partial_stride==0 -> atomicAdd into fp32 C.
template<int BN, int LDA, int LDB>
__global__ __launch_bounds__(256)
void gemm5_kernel(const u16* __restrict__ A, const u16* __restrict__ Bt,
                  const float* __restrict__ bias,
                  const float* __restrict__ resid, int ldr,
                  float* __restrict__ C, int ldc,
                  u16* __restrict__ aux, int auxN,
                  int partial_stride, int Nact, int K, int act) {
  constexpr int WN = BN / 32;            // n-frags per wave
  constexpr int AHALF = 128 * 32;        // 8KB per A buffer
  constexpr int BHALF = BN * 32;
  __shared__ __align__(16) u16 As[2 * AHALF];
  __shared__ __align__(16) u16 Bs[2 * BHALF];
  const int tid = threadIdx.x, lane = tid & 63, wid = tid >> 6;
  const int wr = wid >> 1, wc = wid & 1;
  // bijective XCD-chunked swizzle, column-major within chunk (B-panel L2 reuse)
  int nwg = gridDim.x * gridDim.y;
  int bid = blockIdx.y * gridDim.x + blockIdx.x;
  int swz = (bid & 7) * (nwg >> 3) + (bid >> 3);
  int bx = swz / gridDim.y, by = swz % gridDim.y;
  const int bm = by * 128, bn = bx * BN;
  const int kper = K / gridDim.z;
  const int kbeg = blockIdx.z * kper;
  const int nt = kper / 32;

  int a_src[2], b_src[BN / 64];
#pragma unroll
  for (int j = 0; j < 2; ++j) {
    int c = tid + j * 256;
    int row = c >> 2, kc = (c & 3) ^ ((row + (row >> 2)) & 3);
    a_src[j] = (bm + row) * LDA + kc * 8 + kbeg;
  }
#pragma unroll
  for (int j = 0; j < BN / 64; ++j) {
    int c = tid + j * 256;
    int row = c >> 2, kc = (c & 3) ^ ((row + (row >> 2)) & 3);
    b_src[j] = (bn + row) * LDB + kc * 8 + kbeg;
  }
  int afo[4], bfo[WN];
  const int ch = lane >> 4;
#pragma unroll
  for (int m = 0; m < 4; ++m) {
    int r = wr * 64 + m * 16 + (lane & 15);
    afo[m] = r * 32 + ((ch ^ ((r + (r >> 2)) & 3)) << 3);
  }
#pragma unroll
  for (int n = 0; n < WN; ++n) {
    int r = wc * (BN / 2) + n * 16 + (lane & 15);
    bfo[n] = r * 32 + ((ch ^ ((r + (r >> 2)) & 3)) << 3);
  }
  f32x4 acc[4][WN] = {};

  auto stage = [&](int t, int abuf, int bbuf) {
    int k0 = t * 32;
#pragma unroll
    for (int j = 0; j < 2; ++j)
      gload16(A + a_src[j] + k0, As + abuf + (tid + j * 256) * 8);
#pragma unroll
    for (int j = 0; j < BN / 64; ++j)
      gload16(Bt + b_src[j] + k0, Bs + bbuf + (tid + j * 256) * 8);
  };
  auto compute = [&](int abuf, int bbuf) {
    short8 af[4], bfr[WN];
#pragma unroll
    for (int m = 0; m < 4; ++m) af[m] = *(const short8*)&As[abuf + afo[m]];
#pragma unroll
    for (int n = 0; n < WN; ++n) bfr[n] = *(const short8*)&Bs[bbuf + bfo[n]];
#pragma unroll
    for (int m = 0; m < 4; ++m)
#pragma unroll
      for (int n = 0; n < WN; ++n)
        acc[m][n] = __builtin_amdgcn_mfma_f32_16x16x32_bf16(af[m], bfr[n], acc[m][n], 0, 0, 0);
  };

  stage(0, 0, 0);
  __syncthreads();
  int t = 0;
  while (true) {
    if (t + 1 < nt) stage(t + 1, AHALF, BHALF);
    compute(0, 0);
    __syncthreads();
    if (++t == nt) break;
    if (t + 1 < nt) stage(t + 1, 0, 0);
    compute(AHALF, BHALF);
    __syncthreads();
    if (++t == nt) break;
  }

  const int fr = lane & 15, fq = lane >> 4;
  const int ksegs = gridDim.z;
  u16* Cp = (u16*)C + (size_t)blockIdx.z * partial_stride;
#pragma unroll
  for (int m = 0; m < 4; ++m) {
#pragma unroll
    for (int n = 0; n < WN; ++n) {
#pragma unroll
      for (int j = 0; j < 4; ++j) {
        int row = bm + wr * 64 + m * 16 + fq * 4 + j;
        int col = bn + wc * (BN / 2) + n * 16 + fr;
        if (col < Nact) {
          float v = acc[m][n][j];
          if (ksegs == 1) {
            if (bias) v += bias[col];
            if (resid) v += resid[(size_t)row * ldr + col];
            if (act == 1) v = (v > 20.f) ? v : log1pf(__expf(v));  // softplus
            if (C) C[(size_t)row * ldc + col] = v;
            if (aux && col < auxN) aux[(size_t)row * auxN + col] = f2bf(v);
          } else if (partial_stride > 0) {
            Cp[(size_t)row * ldc + col] = f2bf(v);   // bf16 partial slab
          } else {
            atomicAdd(&C[(size_t)row * ldc + col], v);
          }
        }
      }
    }
  }
}

// ---------------- causal depthwise conv (K=4) + silu -> bf16, x8 vectorized ----------------
__global__ __launch_bounds__(256)
void conv_silu_kernel(const u16* __restrict__ xz, const float* __restrict__ w,
                      const float* __restrict__ cb, u16* __restrict__ xcb) {
  int idx = blockIdx.x * 256 + threadIdx.x;  // CB*CS*CDI/8 = 524288
  int d0 = (idx & 255) * 8;
  int t = (idx >> 8) & (CS - 1);
  int b = idx >> 18;
  const u16* base = xz + (size_t)(b * CS) * 4096 + d0;
  float acc[8];
  float4 cb2[2] = { ((const float4*)(cb + d0))[0], ((const float4*)(cb + d0))[1] };
#pragma unroll
  for (int i = 0; i < 8; ++i) acc[i] = ((const float*)cb2)[i];
#pragma unroll
  for (int k = 0; k < 4; ++k) {
    int tt = t - 3 + k;
    if (tt >= 0) {
      short8 v = *(const short8*)(base + (size_t)tt * 4096);
#pragma unroll
      for (int i = 0; i < 8; ++i)
        acc[i] = fmaf(bf2f((u16)v[i]), w[(d0 + i) * 4 + k], acc[i]);
    }
  }
  short8 o;
#pragma unroll
  for (int i = 0; i < 8; ++i) {
    float v = acc[i] * (1.f / (1.f + __expf(-acc[i])));
    o[i] = (short)f2bf(v);
  }
  *(short8*)(xcb + (size_t)(b * CS + t) * CDI + d0) = o;
}

// ---------------- dbc combine: sum 16 bf16 partial slabs -> dbc fp32 + dtr_bf ----------------
__global__ __launch_bounds__(256)
void dbc_combine_kernel(const u16* __restrict__ parts, float* __restrict__ dbc,
                        u16* __restrict__ dtrb) {
  int idx = blockIdx.x * 256 + threadIdx.x;  // 2048 * 24
  int row = idx / 24, c4 = idx % 24;
  int o = row * 96 + c4 * 4;
  float4 s = make_float4(0.f, 0.f, 0.f, 0.f);
#pragma unroll
  for (int z = 0; z < 16; ++z) {
    ushort4 v = *(const ushort4*)(parts + (size_t)z * (2048 * 96) + o);
    s.x += bf2f(v.x); s.y += bf2f(v.y); s.z += bf2f(v.z); s.w += bf2f(v.w);
  }
  *(float4*)(dbc + o) = s;
  if (c4 < 16) {
    ushort4 b;
    b.x = f2bf(s.x); b.y = f2bf(s.y); b.z = f2bf(s.z); b.w = f2bf(s.w);
    *(ushort4*)(dtrb + row * 64 + c4 * 4) = b;
  }
}

// ---------------- selective scan: thread per (b,chunk,d), N=16 in registers ----------------
__global__ __launch_bounds__(256)
void scan1_kernel(const u16* __restrict__ dtb, const u16* __restrict__ xcb,
                  const float* __restrict__ dbc, const float* __restrict__ A_log,
                  u16* __restrict__ P, u16* __restrict__ Q) {
  int gid = blockIdx.x * 256 + threadIdx.x;  // CB*CNC2*CDI = 262144
  int d = gid & (CDI - 1);
  int c = (gid >> 11) & (CNC2 - 1);
  int b = gid >> 17;
  float acoef[16];
#pragma unroll
  for (int j = 0; j < 4; ++j) {
    float4 al = ((const float4*)(A_log + d * 16))[j];
    acoef[j * 4 + 0] = -__expf(al.x);
    acoef[j * 4 + 1] = -__expf(al.y);
    acoef[j * 4 + 2] = -__expf(al.z);
    acoef[j * 4 + 3] = -__expf(al.w);
  }
  float Pv[16], Qv[16];
#pragma unroll
  for (int n = 0; n < 16; ++n) { Pv[n] = 1.f; Qv[n] = 0.f; }
  size_t rowbase = (size_t)b * CS + (size_t)c * CL2;
  for (int i = 0; i < CL2; ++i) {
    size_t r = rowbase + i;
    float dtv = bf2f(dtb[r * CDI + d]);
    float xcv = bf2f(xcb[r * CDI + d]);
    float dx = dtv * xcv;
    const float4* bs4 = (const float4*)(dbc + r * 96 + 64);
    float bs[16];
#pragma unroll
    for (int j = 0; j < 4; ++j) {
      float4 t4 = bs4[j];
      bs[j * 4 + 0] = t4.x; bs[j * 4 + 1] = t4.y; bs[j * 4 + 2] = t4.z; bs[j * 4 + 3] = t4.w;
    }
#pragma unroll
    for (int n = 0; n < 16; ++n) {
      float a = __expf(dtv * acoef[n]);
      Pv[n] *= a;
      Qv[n] = fmaf(a, Qv[n], dx * bs[n]);
    }
  }
  size_t o = (((size_t)b * CNC2 + c) * CDI + d) * 16;
  u16 pb[16], qb[16];
#pragma unroll
  for (int n = 0; n < 16; ++n) { pb[n] = f2bf(Pv[n]); qb[n] = f2bf(Qv[n]); }
#pragma unroll
  for (int j = 0; j < 2; ++j) {
    *(short8*)(P + o + j * 8) = *(short8*)(pb + j * 8);
    *(short8*)(Q + o + j * 8) = *(short8*)(qb + j * 8);
  }
}

__global__ __launch_bounds__(256)
void scan2_kernel(const u16* __restrict__ P, u16* __restrict__ Q) {
  int gid = blockIdx.x * 256 + threadIdx.x;  // CB*CDI*16 = 65536
  int n = gid & 15;
  int d = (gid >> 4) & (CDI - 1);
  int b = gid >> 15;
  int obase = ((b * CNC2) * CDI + d) * 16 + n;
  constexpr int CSTRIDE = CDI * 16;
  float h = 0.f;
  for (int c0 = 0; c0 < CNC2; c0 += 8) {
    float pv[8], qv[8];
#pragma unroll
    for (int i = 0; i < 8; ++i) {
      int o = obase + (c0 + i) * CSTRIDE;
      pv[i] = bf2f(P[o]);
      qv[i] = bf2f(Q[o]);
    }
#pragma unroll
    for (int i = 0; i < 8; ++i) {
      int o = obase + (c0 + i) * CSTRIDE;
      Q[o] = f2bf(h);
      h = fmaf(pv[i], h, qv[i]);
    }
  }
}

__global__ __launch_bounds__(256)
void scan3_kernel(const u16* __restrict__ dtb, const u16* __restrict__ xcb,
                  const float* __restrict__ dbc, const float* __restrict__ A_log,
                  const u16* __restrict__ Q, const u16* __restrict__ xz,
                  const float* __restrict__ Dskip, u16* __restrict__ y2b) {
  int gid = blockIdx.x * 256 + threadIdx.x;  // 262144
  int d = gid & (CDI - 1);
  int c = (gid >> 11) & (CNC2 - 1);
  int b = gid >> 17;
  float acoef[16];
#pragma unroll
  for (int j = 0; j < 4; ++j) {
    float4 al = ((const float4*)(A_log + d * 16))[j];
    acoef[j * 4 + 0] = -__expf(al.x);
    acoef[j * 4 + 1] = -__expf(al.y);
    acoef[j * 4 + 2] = -__expf(al.z);
    acoef[j * 4 + 3] = -__expf(al.w);
  }
  float h[16];
  size_t o = (((size_t)b * CNC2 + c) * CDI + d) * 16;
#pragma unroll
  for (int j = 0; j < 2; ++j) {
    short8 q8 = *(const short8*)(Q + o + j * 8);
#pragma unroll
    for (int n = 0; n < 8; ++n) h[j * 8 + n] = bf2f((u16)q8[n]);
  }
  float dsk = Dskip[d];
  size_t rowbase = (size_t)b * CS + (size_t)c * CL2;
  for (int i = 0; i < CL2; ++i) {
    size_t r = rowbase + i;
    float dtv = bf2f(dtb[r * CDI + d]);
    float xcv = bf2f(xcb[r * CDI + d]);
    float zv = bf2f(xz[r * 4096 + 2048 + d]);
    float dx = dtv * xcv;
    const float4* bc4 = (const float4*)(dbc + r * 96 + 64);
    float bs[16], cs[16];
#pragma unroll
    for (int j = 0; j < 4; ++j) {
      float4 t4 = bc4[j];
      bs[j * 4 + 0] = t4.x; bs[j * 4 + 1] = t4.y; bs[j * 4 + 2] = t4.z; bs[j * 4 + 3] = t4.w;
      float4 u4 = bc4[4 + j];
      cs[j * 4 + 0] = u4.x; cs[j * 4 + 1] = u4.y; cs[j * 4 + 2] = u4.z; cs[j * 4 + 3] = u4.w;
    }
    float y = 0.f;
#pragma unroll
    for (int n = 0; n < 16; ++n) {
      float a = __expf(dtv * acoef[n]);
      h[n] = fmaf(a, h[n], dx * bs[n]);
      y = fmaf(h[n], cs[n], y);
    }
    float sz = zv * (1.f / (1.f + __expf(-zv)));
    y2b[r * CDI + d] = f2bf((y + xcv * dsk) * sz);
  }
}

// ---------------- soliton stencil -> bf16 (u = S2a + S2b bf16 slabs; b_si added to u0
// only — a per-d constant bias cancels exactly in the ux/uxx/uxxx stencils) ----------------
__global__ __launch_bounds__(256)
void soliton_kernel(const u16* __restrict__ S, const float* __restrict__ bsi,
                    const float* __restrict__ gates, const float* __restrict__ alpha,
                    u16* __restrict__ sol) {
  constexpr size_t SSTR = (size_t)2048 * 1024;
  int idx = blockIdx.x * 256 + threadIdx.x;  // CB*CS*CD = 2M
  int d = idx & (CD - 1);
  int t = (idx >> 10) & (CS - 1);
  int b = idx >> 20;
  int h = d >> 6;
  size_t base = (size_t)b * CS * CD + d;
  int tm2 = max(t - 2, 0), tm1 = max(t - 1, 0);
  int tp1 = min(t + 1, CS - 1), tp2 = min(t + 2, CS - 1);
  auto val = [&](int tt) {
    size_t off = base + (size_t)tt * CD;
    return bf2f(S[off]) + bf2f(S[SSTR + off]);
  };
  float um2 = val(tm2);
  float um1 = val(tm1);
  float u0r = val(t);
  float up1 = val(tp1);
  float up2 = val(tp2);
  float u0 = u0r + bsi[d];
  float ux   = (up1 - um1) * 0.5f;
  float uxx  = up1 - 2.f * u0r + um1;
  float uxxx = (up2 - 2.f * up1 + 2.f * um1 - um2) * 0.5f;
  float sg = sinf(u0);
  float kdv = -6.f * u0 * ux - uxxx;
  float hj = (1.f + alpha[h] * u0) * uxx;
  float du = gates[h * 3 + 0] * sg + gates[h * 3 + 1] * kdv + gates[h * 3 + 2] * hj;
  sol[idx] = f2bf(0.1f * du);
}

extern "C" void kernel_launch(void* const* d_in, const int* in_sizes, int n_in,
                              void* d_out, int out_size, void* d_ws, size_t ws_size,
                              hipStream_t stream) {
  const float* x      = (const float*)d_in[0];
  const float* ln1_g  = (const float*)d_in[1];
  const float* ln1_b  = (const float*)d_in[2];
  const float* W_in   = (const float*)d_in[3];
  const float* b_in   = (const float*)d_in[4];
  const float* conv_w = (const float*)d_in[5];
  const float* conv_b = (const float*)d_in[6];
  const float* W_xp   = (const float*)d_in[7];
  const float* W_dt   = (const float*)d_in[8];
  const float* b_dt   = (const float*)d_in[9];
  const float* A_log  = (const float*)d_in[10];
  const float* D_skip = (const float*)d_in[11];
  const float* W_out  = (const float*)d_in[12];
  const float* b_out  = (const float*)d_in[13];
  const float* ln2_g  = (const float*)d_in[14];
  const float* ln2_b  = (const float*)d_in[15];
  const float* W_si   = (const float*)d_in[16];
  const float* b_si   = (const float*)d_in[17];
  const float* gates  = (const float*)d_in[18];
  const float* alpha  = (const float*)d_in[19];
  const float* W_so   = (const float*)d_in[20];
  const float* b_so   = (const float*)d_in[21];
  float* out = (float*)d_out;

  float* ws = (float*)d_ws;
  size_t off = 0;
  auto alloc = [&](size_t nwords) { float* p = ws + off; off += nwords; return p; };
  const size_t BS = (size_t)CB * CS;  // 2048 rows
  const size_t M1 = 1024 * 1024;

  u16* Wt_in  = (u16*)alloc(2 * M1);       // 4096x1024 bf16
  u16* Wt_xp  = (u16*)alloc(128 * 1024);   // 128x2048 bf16 (padded 96->128)
  u16* Wt_dt  = (u16*)alloc(64 * 1024);    // 2048x64 bf16
  u16* Wt_out = (u16*)alloc(M1);           // 1024x2048 bf16
  u16* Wt_si  = (u16*)alloc(M1 / 2);       // 1024x1024 bf16
  u16* Wt_so  = (u16*)alloc(M1 / 2);
  u16* u_bf   = (u16*)alloc(M1);           // 2048x1024 bf16; alias sol_bf
  u16* sol_bf = u_bf;
  u16* xz_bf  = (u16*)alloc(4 * M1);       // 2048x4096 bf16 (xp | z)
  u16* dt_bf  = (u16*)alloc(2 * M1);       // 2048x2048 bf16
  u16* xc_bf  = (u16*)alloc(2 * M1);       // 2048x2048 bf16
  float* dbc  = alloc(BS * 96);
  u16* dtr_bf = (u16*)alloc(64 * 1024);    // 2048x64 bf16
  float* Pb_f = alloc(2 * M1);             // 8MB: partial slabs / scan P
  float* Qb_f = alloc(2 * M1);             // 8MB: partial slabs spill / scan Q
  u16* Pb = (u16*)Pb_f;
  u16* Qb = (u16*)Qb_f;
  u16* Slab = (u16*)Pb_f;                  // bf16 partial-slab base (up to 4 x 2M u16)
  u16* y2_bf  = (u16*)alloc(2 * M1);       // 2048x2048 bf16

  dim3 blk(256);
  const int PSTRIDE = (int)(BS * CD);      // 2M u16 per split-K partial slab
  const int DBC_STRIDE = 2048 * 96;        // u16 per dbc partial slab

  // 0. weight transposes + LN1 fused in one dispatch
  {
    TJobs jobs;
    int base = 0;
    auto mk = [&](const float* s, u16* dst, int K, int N, int Npad) {
      int gx = Npad / 32, gy = K / 32;
      TJob j{s, dst, K, N, gx, base};
      base += gx * gy;
      return j;
    };
    jobs.j[0] = mk(W_in, Wt_in, 1024, 4096, 4096);
    jobs.j[1] = mk(W_xp, Wt_xp, 2048, 96, 128);
    jobs.j[2] = mk(W_dt, Wt_dt, 64, 2048, 2048);
    jobs.j[3] = mk(W_out, Wt_out, 2048, 1024, 1024);
    jobs.j[4] = mk(W_si, Wt_si, 1024, 1024, 1024);
    jobs.j[5] = mk(W_so, Wt_so, 1024, 1024, 1024);
    transpose_ln_kernel<<<base + (int)BS, blk, 0, stream>>>(jobs, base, x, ln1_g, ln1_b, u_bf);
  }

  // 1. xz = u @ W_in + b_in -> bf16 (1024 blocks, 24KB LDS)
  gemm5_kernel<64, 1024, 1024><<<dim3(64, 16), blk, 0, stream>>>(
      u_bf, Wt_in, b_in, nullptr, 0, nullptr, 0, xz_bf, 4096, 0, 4096, 1024, 0);
  // 2. xc = silu(conv(xp) + conv_b) -> bf16 (x8 vectorized)
  conv_silu_kernel<<<(BS * CDI) / (256 * 8), blk, 0, stream>>>(xz_bf, conv_w, conv_b, xc_bf);
  // 3. dbc partials: split-K=16, bf16 slabs into Slab (512 blocks)
  gemm5_kernel<64, 2048, 2048><<<dim3(2, 16, 16), blk, 0, stream>>>(
      xc_bf, Wt_xp, nullptr, nullptr, 0, (float*)Slab, 96, nullptr, 0, DBC_STRIDE, 96, 2048, 0);
  // 4. combine slabs -> dbc fp32 + dtr_bf
  dbc_combine_kernel<<<(2048 * 24) / 256, blk, 0, stream>>>(Slab, dbc, dtr_bf);
  // 5. dt = softplus(dtr @ W_dt + b_dt) -> bf16 (512 blocks)
  gemm5_kernel<64, 64, 64><<<dim3(32, 16), blk, 0, stream>>>(
      dtr_bf, Wt_dt, b_dt, nullptr, 0, nullptr, 0, dt_bf, 2048, 0, 2048, 64, 1);
  // 6-8. chunked selective scan (N in registers; overwrites Pb/Qb)
  scan1_kernel<<<(CB * CNC2 * CDI) / 256, blk, 0, stream>>>(dt_bf, xc_bf, dbc, A_log, Pb, Qb);
  scan2_kernel<<<(CB * CDI * 16) / 256, blk, 0, stream>>>(Pb, Qb);
  scan3_kernel<<<(CB * CNC2 * CDI) / 256, blk, 0, stream>>>(dt_bf, xc_bf, dbc, A_log, Qb, xz_bf, D_skip, y2_bf);
  // 9. W_out split-K=4 bf16 partials -> Slab[0..3] (1024 blocks)
  gemm5_kernel<64, 2048, 2048><<<dim3(16, 16, 4), blk, 0, stream>>>(
      y2_bf, Wt_out, nullptr, nullptr, 0, (float*)Slab, CD, nullptr, 0, PSTRIDE, 1024, 2048, 0);
  // 10. x1 = x + sum(4 slabs) + b_out -> out; LN2(x1) -> u_bf
  ln_fuse_kernel<<<BS, blk, 0, stream>>>(x, Slab, b_out, ln2_g, ln2_b, out, u_bf);
  // 11. W_si split-K=2 bf16 partials -> Slab[0..1] (b_si added inside soliton)
  gemm5_kernel<64, 1024, 1024><<<dim3(16, 16, 2), blk, 0, stream>>>(
      u_bf, Wt_si, nullptr, nullptr, 0, (float*)Slab, CD, nullptr, 0, PSTRIDE, 1024, 1024, 0);
  // 12. sol = 0.1 * du(slab0 + slab1 + b_si) -> bf16
  soliton_kernel<<<(BS * CD) / 256, blk, 0, stream>>>(Slab, b_si, gates, alpha, sol_bf);
  // 13. W_so split-K=2 bf16 partials -> Slab[0..1]
  gemm5_kernel<64, 1024, 1024><<<dim3(16, 16, 2), blk, 0, stream>>>(
      sol_bf, Wt_so, nullptr, nullptr, 0, (float*)Slab, CD, nullptr, 0, PSTRIDE, 1024, 1024, 0);
  // 14. out = x1 + slab0 + slab1 + b_so
  add3_kernel<<<(BS * CD) / (256 * 4), blk, 0, stream>>>(out, Slab, b_so);
}